// Round 17
// baseline (427.346 us; speedup 1.0000x reference)
//
#include <hip/hip_runtime.h>
#include <math.h>

// TheRecurrentNet: B=512, K=16, H=500, A=64, nc=15.
// Round 17: round-16 champion (418.8 us) + final propagation — gemm_sq gains
// split-A support and takes over the two K=1024 GEMMs (ac_fc2, fc6), where
// the 16-tile-deep counted-vmcnt pipeline amortizes best. s2/fc1 (K=512,
// N=512) stay on the BN=64 kernel. Bit-identical numerics.

#define EPSF 1e-5f
typedef unsigned short u16;
typedef unsigned int u32;

typedef __bf16 bf16x8 __attribute__((ext_vector_type(8)));
typedef float f32x4 __attribute__((ext_vector_type(4)));
typedef u16 u16x8 __attribute__((ext_vector_type(8)));

__device__ __forceinline__ float bf2f(u16 u) {
  return __builtin_bit_cast(float, (u32)u << 16);
}
__device__ __forceinline__ u16 f2bf(float f) {
  u32 u = __builtin_bit_cast(u32, f);
  return (u16)((u + 0x7FFFu + ((u >> 16) & 1u)) >> 16);   // RNE
}

#define GLOAD16(g, l) __builtin_amdgcn_global_load_lds( \
    (__attribute__((address_space(1))) u32*)(g), \
    (__attribute__((address_space(3))) u32*)(l), 16, 0, 0)

// ======================= bf16 MFMA GEMM, 128x64 tile, BK=64 ==================
// C[M,Npad] = A[M,K] @ Bt[Npad,K]^T + bias, optional *rowscale.
// Double-buffered LDS, counted vmcnt, LDS XOR-swizzle, XCD col-fast swizzle.
template <typename TOUT>
__global__ __launch_bounds__(256) void gemm_mfma(
    const u16* __restrict__ A, const u16* __restrict__ A2,
    const u16* __restrict__ Bt,
    const float* __restrict__ bias, const float* __restrict__ rowscale,
    TOUT* __restrict__ C, int M, int Npad, int K, int lda, int khalf)
{
  __shared__ __align__(16) u16 As[2][128 * 64];
  __shared__ __align__(16) u16 Bs[2][64 * 64];
  const int tid = threadIdx.x;
  const int lane = tid & 63, wid = tid >> 6;

  const int ncols = gridDim.x;
  const int nwg = ncols * gridDim.y;
  const int bid = blockIdx.y * ncols + blockIdx.x;
  const int swz = (bid & 7) * (nwg >> 3) + (bid >> 3);
  const size_t row0 = (size_t)(swz / ncols) * 128;
  const size_t col0 = (size_t)(swz % ncols) * 64;

  f32x4 acc[2][4] = {};

  const int s_sub = tid >> 3;
  const int s_chunk = (tid & 7) ^ (s_sub & 7);
  const size_t aoff = (row0 + s_sub) * (size_t)lda + s_chunk * 8;
  const u16* gA = A + aoff;
  const u16* gA2 = A2 ? (A2 + aoff - khalf) : nullptr;
  const u16* gB = Bt + (col0 + s_sub) * (size_t)K + s_chunk * 8;

  const int fr = lane & 15, fq = lane >> 4;
  const int cx0 = fq ^ (fr & 7);
  const int cx1 = (4 + fq) ^ (fr & 7);

  const int nkt = K >> 6;
  int cur = 0;

  {
#pragma unroll
    for (int h = 0; h < 4; ++h)
      GLOAD16(gA + (size_t)h * 32 * lda, &As[0][(h * 256 + tid) * 8]);
#pragma unroll
    for (int h = 0; h < 2; ++h)
      GLOAD16(gB + (size_t)h * 32 * K, &Bs[0][(h * 256 + tid) * 8]);
  }

  for (int kt = 0; kt < nkt; ++kt) {
    if (kt + 1 < nkt) {
      const int kk = (kt + 1) * 64;
      const u16* a = (A2 && kk >= khalf) ? (gA2 + kk) : (gA + kk);
      const u16* b = gB + kk;
#pragma unroll
      for (int h = 0; h < 4; ++h)
        GLOAD16(a + (size_t)h * 32 * lda, &As[cur ^ 1][(h * 256 + tid) * 8]);
#pragma unroll
      for (int h = 0; h < 2; ++h)
        GLOAD16(b + (size_t)h * 32 * K, &Bs[cur ^ 1][(h * 256 + tid) * 8]);
      asm volatile("s_waitcnt vmcnt(6)" ::: "memory");
    } else {
      asm volatile("s_waitcnt vmcnt(0)" ::: "memory");
    }
    __builtin_amdgcn_sched_barrier(0);
    __builtin_amdgcn_s_barrier();
    __builtin_amdgcn_sched_barrier(0);

    const u16* as = As[cur];
    const u16* bs = Bs[cur];
#pragma unroll
    for (int ks = 0; ks < 2; ++ks) {
      const int cx = ks ? cx1 : cx0;
      bf16x8 af[2], bf[4];
#pragma unroll
      for (int m = 0; m < 2; ++m) {
        int row = wid * 32 + m * 16 + fr;
        af[m] = *reinterpret_cast<const bf16x8*>(as + (row * 8 + cx) * 8);
      }
#pragma unroll
      for (int n = 0; n < 4; ++n) {
        int row = n * 16 + fr;
        bf[n] = *reinterpret_cast<const bf16x8*>(bs + (row * 8 + cx) * 8);
      }
#pragma unroll
      for (int m = 0; m < 2; ++m)
#pragma unroll
        for (int n = 0; n < 4; ++n)
          acc[m][n] = __builtin_amdgcn_mfma_f32_16x16x32_bf16(af[m], bf[n], acc[m][n], 0, 0, 0);
    }
    asm volatile("s_waitcnt lgkmcnt(0)" ::: "memory");
    __builtin_amdgcn_sched_barrier(0);
    __builtin_amdgcn_s_barrier();
    __builtin_amdgcn_sched_barrier(0);
    cur ^= 1;
  }

  const int cl = lane & 15, rg = lane >> 4;
#pragma unroll
  for (int m = 0; m < 2; ++m) {
#pragma unroll
    for (int n = 0; n < 4; ++n) {
      size_t col = col0 + n * 16 + cl;
      float bv = bias[col];
#pragma unroll
      for (int r = 0; r < 4; ++r) {
        size_t row = row0 + wid * 32 + m * 16 + rg * 4 + r;
        float v = acc[m][n][r] + bv;
        if (rowscale) v *= rowscale[row];
        if constexpr (sizeof(TOUT) == 2) C[row * Npad + col] = f2bf(v);
        else                             C[row * Npad + col] = v;
      }
    }
  }
}

// ==== bf16 MFMA GEMM, 128x128 tile, BK=64, DOUBLE-buffer + counted vmcnt ====
// 4 waves each own a 64x64 quadrant (4x4 frags). Next K-tile's 8 loads stay
// in flight across the barrier (vmcnt(8)). A2: K-range [khalf,K) reads from
// A2 (split-A concat fusion; khalf=0 disables). 64 KB LDS -> 2 blocks/CU.
template <typename TOUT>
__global__ __launch_bounds__(256) void gemm_sq(
    const u16* __restrict__ A, const u16* __restrict__ A2,
    const u16* __restrict__ Bt,
    const float* __restrict__ bias,
    TOUT* __restrict__ C, int M, int Npad, int K, int lda, int khalf)
{
  __shared__ __align__(16) u16 As[2][128 * 64];
  __shared__ __align__(16) u16 Bs[2][128 * 64];
  const int tid = threadIdx.x;
  const int lane = tid & 63, wid = tid >> 6;
  const int ar0 = (wid >> 1) * 64;   // wave row base
  const int bc0 = (wid & 1) * 64;    // wave col base

  const int ncols = gridDim.x;
  const int nwg = ncols * gridDim.y;
  const int bid = blockIdx.y * ncols + blockIdx.x;
  const int swz = (bid & 7) * (nwg >> 3) + (bid >> 3);
  const size_t row0 = (size_t)(swz / ncols) * 128;
  const size_t col0 = (size_t)(swz % ncols) * 128;

  f32x4 acc[4][4] = {};

  const int s_sub = tid >> 3;
  const int s_chunk = (tid & 7) ^ (s_sub & 7);
  const size_t aoff = (row0 + s_sub) * (size_t)lda + s_chunk * 8;
  const u16* gA = A + aoff;
  const u16* gA2 = A2 ? (A2 + aoff - khalf) : nullptr;
  const u16* gB = Bt + (col0 + s_sub) * (size_t)K + s_chunk * 8;

  const int fr = lane & 15, fq = lane >> 4;
  const int cx0 = fq ^ (fr & 7);
  const int cx1 = (4 + fq) ^ (fr & 7);

  const int nkt = K >> 6;
  int cur = 0;

  // prologue: stage K-tile 0 into buffer 0 (8 loads; kk=0 < khalf -> A)
  {
#pragma unroll
    for (int h = 0; h < 4; ++h) {
      GLOAD16(gA + (size_t)h * 32 * lda, &As[0][(h * 256 + tid) * 8]);
      GLOAD16(gB + (size_t)h * 32 * K,  &Bs[0][(h * 256 + tid) * 8]);
    }
  }

  for (int kt = 0; kt < nkt; ++kt) {
    if (kt + 1 < nkt) {
      const int kk = (kt + 1) * 64;
      const u16* a = (A2 && kk >= khalf) ? (gA2 + kk) : (gA + kk);
      const u16* b = gB + kk;
#pragma unroll
      for (int h = 0; h < 4; ++h) {
        GLOAD16(a + (size_t)h * 32 * lda, &As[cur ^ 1][(h * 256 + tid) * 8]);
        GLOAD16(b + (size_t)h * 32 * K,  &Bs[cur ^ 1][(h * 256 + tid) * 8]);
      }
      asm volatile("s_waitcnt vmcnt(8)" ::: "memory");   // wait tile kt only
    } else {
      asm volatile("s_waitcnt vmcnt(0)" ::: "memory");
    }
    __builtin_amdgcn_sched_barrier(0);
    __builtin_amdgcn_s_barrier();                        // tile kt ready
    __builtin_amdgcn_sched_barrier(0);

    const u16* as = As[cur];
    const u16* bs = Bs[cur];
#pragma unroll
    for (int ks = 0; ks < 2; ++ks) {
      const int cx = ks ? cx1 : cx0;
      bf16x8 af[4], bf[4];
#pragma unroll
      for (int m = 0; m < 4; ++m)
        af[m] = *reinterpret_cast<const bf16x8*>(as + ((ar0 + m * 16 + fr) * 8 + cx) * 8);
#pragma unroll
      for (int n = 0; n < 4; ++n)
        bf[n] = *reinterpret_cast<const bf16x8*>(bs + ((bc0 + n * 16 + fr) * 8 + cx) * 8);
#pragma unroll
      for (int m = 0; m < 4; ++m)
#pragma unroll
        for (int n = 0; n < 4; ++n)
          acc[m][n] = __builtin_amdgcn_mfma_f32_16x16x32_bf16(af[m], bf[n], acc[m][n], 0, 0, 0);
    }
    asm volatile("s_waitcnt lgkmcnt(0)" ::: "memory");
    __builtin_amdgcn_sched_barrier(0);
    __builtin_amdgcn_s_barrier();                        // safe to overwrite buf
    __builtin_amdgcn_sched_barrier(0);
    cur ^= 1;
  }

  const int cl = lane & 15, rg = lane >> 4;
#pragma unroll
  for (int m = 0; m < 4; ++m) {
#pragma unroll
    for (int n = 0; n < 4; ++n) {
      size_t col = col0 + bc0 + n * 16 + cl;
      float bv = bias[col];
#pragma unroll
      for (int r = 0; r < 4; ++r) {
        size_t row = row0 + ar0 + m * 16 + rg * 4 + r;
        float v = acc[m][n][r] + bv;
        if constexpr (sizeof(TOUT) == 2) C[row * Npad + col] = f2bf(v);
        else                             C[row * Npad + col] = v;
      }
    }
  }
}

// ---------------- small f32 GEMM (actions @ ac_fc1_w) ------------------------
__global__ __launch_bounds__(256) void gemm128(
    const float* __restrict__ A, const float* __restrict__ B,
    const float* __restrict__ bias, float* __restrict__ C, int M, int N, int K)
{
  __shared__ float As[16][132];
  __shared__ float Bs[16][128];
  const int tid = threadIdx.x;
  const int tx = tid & 15, ty = tid >> 4;
  const int row0 = blockIdx.y * 128, col0 = blockIdx.x * 128;
  float acc[8][8];
#pragma unroll
  for (int i = 0; i < 8; ++i)
#pragma unroll
    for (int j = 0; j < 8; ++j) acc[i][j] = 0.f;

  const int nkt = (K + 15) >> 4;
  for (int kt = 0; kt < nkt; ++kt) {
    const int k0 = kt << 4;
#pragma unroll
    for (int h = 0; h < 2; ++h) {
      int i = tid + h * 256;
      int m = i >> 2, kk = (i & 3) << 2;
      int gm = row0 + m, gk = k0 + kk;
      float4 v = make_float4(0.f, 0.f, 0.f, 0.f);
      if (gm < M && gk < K) v = *reinterpret_cast<const float4*>(A + (size_t)gm * K + gk);
      As[kk + 0][m] = v.x; As[kk + 1][m] = v.y; As[kk + 2][m] = v.z; As[kk + 3][m] = v.w;
    }
#pragma unroll
    for (int h = 0; h < 2; ++h) {
      int i = tid + h * 256;
      int kk = i >> 5, n = (i & 31) << 2;
      int gk = k0 + kk, gn = col0 + n;
      float4 v = make_float4(0.f, 0.f, 0.f, 0.f);
      if (gk < K && gn < N) v = *reinterpret_cast<const float4*>(B + (size_t)gk * N + gn);
      *reinterpret_cast<float4*>(&Bs[kk][n]) = v;
    }
    __syncthreads();
#pragma unroll
    for (int kk = 0; kk < 16; ++kk) {
      float4 a0 = *reinterpret_cast<const float4*>(&As[kk][ty * 4]);
      float4 a1 = *reinterpret_cast<const float4*>(&As[kk][ty * 4 + 64]);
      float4 b0 = *reinterpret_cast<const float4*>(&Bs[kk][tx * 4]);
      float4 b1 = *reinterpret_cast<const float4*>(&Bs[kk][tx * 4 + 64]);
      float av[8] = {a0.x, a0.y, a0.z, a0.w, a1.x, a1.y, a1.z, a1.w};
      float bv[8] = {b0.x, b0.y, b0.z, b0.w, b1.x, b1.y, b1.z, b1.w};
#pragma unroll
      for (int i = 0; i < 8; ++i)
#pragma unroll
        for (int j = 0; j < 8; ++j) acc[i][j] += av[i] * bv[j];
    }
    __syncthreads();
  }
#pragma unroll
  for (int i = 0; i < 8; ++i) {
    int gm = row0 + ty * 4 + ((i >> 2) << 6) + (i & 3);
    if (gm >= M) continue;
#pragma unroll
    for (int j = 0; j < 8; ++j) {
      int gn = col0 + tx * 4 + ((j >> 2) << 6) + (j & 3);
      if (gn < N) C[(size_t)gm * N + gn] = acc[i][j] + bias[gn];
    }
  }
}

// ------------- wave-per-4-rows LayerNorm (cols=500) --------------------------
template <int ACT, typename TIN, typename TOUT>
__global__ __launch_bounds__(256) void ln_wave4(
    const TIN* __restrict__ X, TOUT* __restrict__ Y,
    const float* __restrict__ g, const float* __restrict__ b,
    int ldx, int ldy)
{
  int w = threadIdx.x >> 6, lane = threadIdx.x & 63;
  int id0 = (blockIdx.x * 4 + w) * 4;
  int k0 = lane * 8;
  float xv[4][8], s[4], s2[4];
#pragma unroll
  for (int r = 0; r < 4; ++r) {
    s[r] = 0.f; s2[r] = 0.f;
    if constexpr (sizeof(TIN) == 2) {
      u16x8 u = *reinterpret_cast<const u16x8*>((const u16*)X + (size_t)(id0 + r) * ldx + k0);
#pragma unroll
      for (int e = 0; e < 8; ++e) xv[r][e] = bf2f(u[e]);
    } else {
      const float* x = (const float*)X + (size_t)(id0 + r) * ldx;
      if (k0 + 8 <= 500) {
        float4 a = *reinterpret_cast<const float4*>(x + k0);
        float4 c = *reinterpret_cast<const float4*>(x + k0 + 4);
        xv[r][0] = a.x; xv[r][1] = a.y; xv[r][2] = a.z; xv[r][3] = a.w;
        xv[r][4] = c.x; xv[r][5] = c.y; xv[r][6] = c.z; xv[r][7] = c.w;
      } else {
#pragma unroll
        for (int e = 0; e < 8; ++e) xv[r][e] = (k0 + e < 500) ? x[k0 + e] : 0.f;
      }
    }
#pragma unroll
    for (int e = 0; e < 8; ++e) { s[r] += xv[r][e]; s2[r] += xv[r][e] * xv[r][e]; }
  }
#pragma unroll
  for (int m = 32; m; m >>= 1)
#pragma unroll
    for (int r = 0; r < 4; ++r) {
      s[r] += __shfl_xor(s[r], m);
      s2[r] += __shfl_xor(s2[r], m);
    }
  float gv[8], bv[8];
#pragma unroll
  for (int e = 0; e < 8; ++e) {
    int k = k0 + e;
    gv[e] = (k < 500) ? g[k] : 0.f;
    bv[e] = (k < 500) ? b[k] : 0.f;
  }
#pragma unroll
  for (int r = 0; r < 4; ++r) {
    float mu = s[r] / 500.f;
    float rstd = rsqrtf(s2[r] / 500.f - mu * mu + EPSF);
    float ov[8];
#pragma unroll
    for (int e = 0; e < 8; ++e) {
      float v = (k0 + e < 500) ? ((xv[r][e] - mu) * rstd * gv[e] + bv[e]) : 0.f;
      if (ACT == 1) v = fmaxf(v, 0.f);
      ov[e] = v;
    }
    if constexpr (sizeof(TOUT) == 2) {
      u16x8 o;
#pragma unroll
      for (int e = 0; e < 8; ++e) o[e] = f2bf(ov[e]);
      *reinterpret_cast<u16x8*>((u16*)Y + (size_t)(id0 + r) * ldy + k0) = o;
    } else {
      float* y = (float*)Y + (size_t)(id0 + r) * ldy;
      if (k0 + 4 <= 500)
        *reinterpret_cast<float4*>(y + k0) = make_float4(ov[0], ov[1], ov[2], ov[3]);
      if (k0 + 8 <= 500)
        *reinterpret_cast<float4*>(y + k0 + 4) = make_float4(ov[4], ov[5], ov[6], ov[7]);
    }
  }
}

// ---------------- cat[r] = [bf16(state[r]) | a[r>>4] | 0pad] -----------------
__global__ __launch_bounds__(256) void build_concat(
    const float* __restrict__ state, const u16* __restrict__ a, u16* __restrict__ cat)
{
  int r = blockIdx.x, t = threadIdx.x;
  int b = r >> 4;
  u16* c = cat + (size_t)r * 1024;
  if (t < 125) {
    float4 v = *reinterpret_cast<const float4*>(state + (size_t)r * 500 + t * 4);
    ushort4 o; o.x = f2bf(v.x); o.y = f2bf(v.y); o.z = f2bf(v.z); o.w = f2bf(v.w);
    *reinterpret_cast<ushort4*>(c + t * 4) = o;
    *reinterpret_cast<ushort4*>(c + 500 + t * 4) =
        *reinterpret_cast<const ushort4*>(a + (size_t)b * 512 + t * 4);
  }
  if (t < 24) c[1000 + t] = 0;
}

// -------- att_a: 4 rows per wave ---------------------------------------------
__global__ __launch_bounds__(256) void dot_sig4(
    const u16* __restrict__ cat, const float* __restrict__ w3,
    const float* __restrict__ b3, float* __restrict__ atta)
{
  int w = threadIdx.x >> 6, lane = threadIdx.x & 63;
  int r0 = (blockIdx.x * 4 + w) * 4;
  int k0 = lane * 16;
  float wv[16];
#pragma unroll
  for (int e = 0; e < 16; ++e) wv[e] = (k0 + e < 1000) ? w3[k0 + e] : 0.f;
  float s[4];
#pragma unroll
  for (int r = 0; r < 4; ++r) {
    const u16* x = cat + (size_t)(r0 + r) * 1024 + k0;
    u16x8 u0 = *reinterpret_cast<const u16x8*>(x);
    u16x8 u1 = *reinterpret_cast<const u16x8*>(x + 8);
    float acc = 0.f;
#pragma unroll
    for (int e = 0; e < 8; ++e) acc += bf2f(u0[e]) * wv[e];
#pragma unroll
    for (int e = 0; e < 8; ++e) acc += bf2f(u1[e]) * wv[8 + e];
    s[r] = acc;
  }
#pragma unroll
  for (int m = 32; m; m >>= 1)
#pragma unroll
    for (int r = 0; r < 4; ++r) s[r] += __shfl_xor(s[r], m);
  if (lane == 0) {
#pragma unroll
    for (int r = 0; r < 4; ++r)
      atta[r0 + r] = 1.f / (1.f + expf(-(s[r] + b3[0])));
  }
}

// -------- core rows = relu(LN(P[r1]+Q[r2], ln2)) — 4 rows/wave, bf16 ---------
__global__ __launch_bounds__(256) void core_build3(
    const u16* __restrict__ PQ, u16* __restrict__ core,
    const float* __restrict__ g2, const float* __restrict__ b2, int c0)
{
  int w = threadIdx.x >> 6, lane = threadIdx.x & 63;
  int id0 = (blockIdx.x * 4 + w) * 4;
  int k0 = lane * 8;
  u16x8 up[4], uq[4];
#pragma unroll
  for (int r = 0; r < 4; ++r) {
    int id = id0 + r;
    int pp = id / 15, j = id - pp * 15;
    int gp = c0 + pp, i = gp & 15;
    int col = j + (j >= i);
    int r2 = (gp & ~15) | col;
    up[r] = *reinterpret_cast<const u16x8*>(PQ + (size_t)gp * 1024 + k0);
    uq[r] = *reinterpret_cast<const u16x8*>(PQ + (size_t)r2 * 1024 + 512 + k0);
  }
  float xv[4][8], s[4], s2[4];
#pragma unroll
  for (int r = 0; r < 4; ++r) {
    s[r] = 0.f; s2[r] = 0.f;
#pragma unroll
    for (int e = 0; e < 8; ++e) {
      float v = bf2f(up[r][e]) + bf2f(uq[r][e]);   // pads are exact zeros
      xv[r][e] = v; s[r] += v; s2[r] += v * v;
    }
  }
#pragma unroll
  for (int m = 32; m; m >>= 1)
#pragma unroll
    for (int r = 0; r < 4; ++r) {
      s[r] += __shfl_xor(s[r], m);
      s2[r] += __shfl_xor(s2[r], m);
    }
  float gv[8], bv[8];
#pragma unroll
  for (int e = 0; e < 8; ++e) {
    int k = k0 + e;
    gv[e] = (k < 500) ? g2[k] : 0.f;
    bv[e] = (k < 500) ? b2[k] : 0.f;
  }
#pragma unroll
  for (int r = 0; r < 4; ++r) {
    float mu = s[r] / 500.f;
    float rstd = rsqrtf(s2[r] / 500.f - mu * mu + EPSF);
    u16x8 o;
#pragma unroll
    for (int e = 0; e < 8; ++e)
      o[e] = (k0 + e < 500) ? f2bf(fmaxf((xv[r][e] - mu) * rstd * gv[e] + bv[e], 0.f)) : (u16)0;
    *reinterpret_cast<u16x8*>(core + (size_t)(id0 + r) * 512 + k0) = o;
  }
}

// -------- fused chunk tail -> esum in PADDED BF16 (feeds fc6 split-A) --------
__global__ __launch_bounds__(256) void chunk_post3(
    const u16* __restrict__ V,
    const float* __restrict__ g3, const float* __restrict__ b3,
    const float* __restrict__ g4, const float* __restrict__ b4,
    const float* __restrict__ w5, const float* __restrict__ b5,
    u16* __restrict__ esum16, int c0)
{
  __shared__ u16 rows[15][512];
  __shared__ float st[15][4];   // mu, rstd, att
  int pp = blockIdx.x, t = threadIdx.x;
  int lane = t & 63, w = t >> 6;
  int k0 = lane * 8;
  int kk = lane * 2;

  u16x8 u[4]; ushort2 ua[4];
#pragma unroll
  for (int r = 0; r < 4; ++r) {
    int j = w * 4 + r;
    if (j < 15) {
      const u16* vr = V + (size_t)(pp * 15 + j) * 640;
      u[r] = *reinterpret_cast<const u16x8*>(vr + k0);
      ua[r] = *reinterpret_cast<const ushort2*>(vr + 512 + kk);
    }
  }
  float s[4], s2[4], sa[4], sa2[4], y0[4], y1[4];
#pragma unroll
  for (int r = 0; r < 4; ++r) {
    s[r] = s2[r] = sa[r] = sa2[r] = 0.f; y0[r] = y1[r] = 0.f;
    int j = w * 4 + r;
    if (j < 15) {
#pragma unroll
      for (int e = 0; e < 8; ++e) { float v = bf2f(u[r][e]); s[r] += v; s2[r] += v * v; }
      y0[r] = bf2f(ua[r].x); y1[r] = bf2f(ua[r].y);
      sa[r] = y0[r] + y1[r]; sa2[r] = y0[r] * y0[r] + y1[r] * y1[r];
      *reinterpret_cast<u16x8*>(&rows[j][k0]) = u[r];
    }
  }
#pragma unroll
  for (int m = 32; m; m >>= 1)
#pragma unroll
    for (int r = 0; r < 4; ++r) {
      s[r]   += __shfl_xor(s[r], m);
      s2[r]  += __shfl_xor(s2[r], m);
      sa[r]  += __shfl_xor(sa[r], m);
      sa2[r] += __shfl_xor(sa2[r], m);
    }
  float dv[4];
#pragma unroll
  for (int r = 0; r < 4; ++r) {
    float mu4 = sa[r] / 100.f;
    float rstd4 = rsqrtf(sa2[r] / 100.f - mu4 * mu4 + EPSF);
    float d = 0.f;
    if (kk < 100)     d += tanhf((y0[r] - mu4) * rstd4 * g4[kk] + b4[kk]) * w5[kk];
    if (kk + 1 < 100) d += tanhf((y1[r] - mu4) * rstd4 * g4[kk + 1] + b4[kk + 1]) * w5[kk + 1];
    dv[r] = d;
  }
#pragma unroll
  for (int m = 32; m; m >>= 1)
#pragma unroll
    for (int r = 0; r < 4; ++r) dv[r] += __shfl_xor(dv[r], m);
  if (lane == 0) {
#pragma unroll
    for (int r = 0; r < 4; ++r) {
      int j = w * 4 + r;
      if (j < 15) {
        float mu = s[r] / 500.f;
        st[j][0] = mu;
        st[j][1] = rsqrtf(s2[r] / 500.f - mu * mu + EPSF);
        st[j][2] = 1.f / (1.f + expf(-(dv[r] + b5[0])));
      }
    }
  }
  __syncthreads();

  u16* o = esum16 + (size_t)(c0 + pp) * 512;
  for (int n = t; n < 500; n += 256) {
    float gg = g3[n], bb = b3[n], acc = 0.f;
#pragma unroll
    for (int j = 0; j < 15; ++j) {
      float v = bf2f(rows[j][n]);
      acc += fmaxf((v - st[j][0]) * st[j][1] * gg + bb, 0.f) * st[j][2];
    }
    o[n] = f2bf(acc);
  }
  if (t < 12) o[500 + t] = 0;
}

// -------- merged transpose+pack: all 9 weight jobs in one dispatch -----------
struct TJob {
  const float* src; u16* dst;
  int K, N, srcLd, ldDst, nOff, kOff, tileBase, tilesX;
};
struct TJobs { TJob j[9]; int total; };

__global__ void pack_weights(TJobs jobs)
{
  __shared__ float tl[32][33];
  int bid = blockIdx.x;
  int ji = 0;
#pragma unroll
  for (int q = 1; q < 9; ++q) if (bid >= jobs.j[q].tileBase) ji = q;
  const TJob& J = jobs.j[ji];
  int t = bid - J.tileBase;
  int bx = t % J.tilesX, by = t / J.tilesX;
  int tx = threadIdx.x, ty = threadIdx.y;   // 32 x 8
  int k0 = by * 32, n0 = bx * 32;
#pragma unroll
  for (int r = 0; r < 4; ++r) {
    int row = k0 + ty + r * 8;
    if (row < J.K && n0 + tx < J.N) tl[ty + r * 8][tx] = J.src[(size_t)row * J.srcLd + n0 + tx];
  }
  __syncthreads();
#pragma unroll
  for (int r = 0; r < 4; ++r) {
    int n = n0 + ty + r * 8, k = k0 + tx;
    if (n < J.N && k < J.K)
      J.dst[(size_t)(n + J.nOff) * J.ldDst + J.kOff + k] = f2bf(tl[tx][ty + r * 8]);
  }
}

// -------- pack padded biases --------------------------------------------------
__global__ void pack_biases(
    const float* ac2, const float* lnf2, const float* f1, const float* f2,
    const float* f3, const float* f4, const float* f6,
    float* b_ac2p, float* b_lnf2p, float* b_f1p, float* b2p, float* b34p, float* b_f6p)
{
  int t = threadIdx.x;  // 1024
  switch (blockIdx.x) {
    case 0: if (t < 512) b_ac2p[t]  = (t < 500) ? ac2[t]  : 0.f; break;
    case 1: if (t < 512) b_lnf2p[t] = (t < 500) ? lnf2[t] : 0.f; break;
    case 2: if (t < 512) b_f1p[t]   = (t < 500) ? f1[t]   : 0.f; break;
    case 3: b2p[t] = (t < 500) ? f2[t] : 0.f; break;
    case 4: if (t < 640) b34p[t] = (t < 500) ? f3[t] : ((t >= 512 && t < 612) ? f4[t - 512] : 0.f); break;
    case 5: if (t < 512) b_f6p[t]   = (t < 500) ? f6[t]   : 0.f; break;
  }
}

extern "C" void kernel_launch(void* const* d_in, const int* in_sizes, int n_in,
                              void* d_out, int out_size, void* d_ws, size_t ws_size,
                              hipStream_t stream)
{
  const float* state    = (const float*)d_in[0];
  const float* actions  = (const float*)d_in[1];
  const float* ac_fc1_w = (const float*)d_in[2];
  const float* ac_fc1_b = (const float*)d_in[3];
  const float* ac_ln1_g = (const float*)d_in[4];
  const float* ac_ln1_b = (const float*)d_in[5];
  const float* ac_fc2_w = (const float*)d_in[6];
  const float* ac_fc2_b = (const float*)d_in[7];
  const float* ac_lnf2_w= (const float*)d_in[8];
  const float* ac_lnf2_b= (const float*)d_in[9];
  const float* ac_fc3_w = (const float*)d_in[10];
  const float* ac_fc3_b = (const float*)d_in[11];
  const float* fc1_w = (const float*)d_in[12];
  const float* fc1_b = (const float*)d_in[13];
  const float* ln1_g = (const float*)d_in[14];
  const float* ln1_b = (const float*)d_in[15];
  const float* fc2_w = (const float*)d_in[16];
  const float* fc2_b = (const float*)d_in[17];
  const float* ln2_g = (const float*)d_in[18];
  const float* ln2_b = (const float*)d_in[19];
  const float* fc3_w = (const float*)d_in[20];
  const float* fc3_b = (const float*)d_in[21];
  const float* ln3_g = (const float*)d_in[22];
  const float* ln3_b = (const float*)d_in[23];
  const float* fc4_w = (const float*)d_in[24];
  const float* fc4_b = (const float*)d_in[25];
  const float* ln4_g = (const float*)d_in[26];
  const float* ln4_b = (const float*)d_in[27];
  const float* fc5_w = (const float*)d_in[28];
  const float* fc5_b = (const float*)d_in[29];
  const float* fc6_w = (const float*)d_in[30];
  const float* fc6_b = (const float*)d_in[31];
  const float* ln6_g = (const float*)d_in[32];
  const float* ln6_b = (const float*)d_in[33];
  float* out = (float*)d_out;

  // ---- ws carve (bytes, 256-aligned); total ~215 MB ----
  char* p = (char*)d_ws;
  auto carve = [&](size_t bytes) { char* r = p; p += (bytes + 255) & ~(size_t)255; return r; };
  u16*   cat    = (u16*)  carve(8192ull * 1024 * 2);
  u16*   t1     = (u16*)  carve(8192ull * 512 * 2);    // ac_fc2 out, later fc1/fc6 pre-LN
  u16*   s2     = (u16*)  carve(8192ull * 512 * 2);
  u16*   s1     = (u16*)  carve(8192ull * 512 * 2);
  u16*   core   = (u16*)  carve(61440ull * 512 * 2);
  u16*   v      = (u16*)  carve(61440ull * 640 * 2);
  u16*   PQ     = (u16*)  carve(8192ull * 1024 * 2);
  u16*   esum16 = (u16*)  carve(8192ull * 512 * 2);
  u16*   a_buf  = (u16*)  carve(512ull * 512 * 2);
  float* tmp_a  = (float*)carve(512ull * 500 * 4);
  float* att_a  = (float*)carve(8192ull * 4);
  char*  wT0    =         carve(0);
  u16*   ac_fc2T  = (u16*)carve(512ull * 1024 * 2);
  u16*   ac_lnf2T = (u16*)carve(512ull * 512 * 2);
  u16*   fc1T     = (u16*)carve(512ull * 512 * 2);
  u16*   B2T      = (u16*)carve(1024ull * 512 * 2);
  u16*   B34T     = (u16*)carve(640ull * 512 * 2);
  u16*   fc6T     = (u16*)carve(512ull * 1024 * 2);
  size_t wTbytes  = (size_t)((char*)carve(0) - wT0);
  float* b_ac2p  = (float*)carve(512 * 4);
  float* b_lnf2p = (float*)carve(512 * 4);
  float* b_f1p   = (float*)carve(512 * 4);
  float* b2p     = (float*)carve(1024 * 4);
  float* b34p    = (float*)carve(640 * 4);
  float* b_f6p   = (float*)carve(512 * 4);

  dim3 blk(256);
  dim3 tblk(32, 8);

  // ---- weight packing: one memset + one merged transpose dispatch ----
  hipMemsetAsync(wT0, 0, wTbytes, stream);
  TJobs jobs;
  int base = 0;
  auto addjob = [&](int idx, const float* src, u16* dst, int K, int N, int srcLd,
                    int ldDst, int nOff, int kOff) {
    int tx = (N + 31) / 32, ty = (K + 31) / 32;
    jobs.j[idx] = {src, dst, K, N, srcLd, ldDst, nOff, kOff, base, tx};
    base += tx * ty;
  };
  addjob(0, ac_fc2_w,         ac_fc2T,  1000, 500, 500, 1024, 0, 0);
  addjob(1, ac_lnf2_w,        ac_lnf2T,  500, 500, 500,  512, 0, 0);
  addjob(2, fc1_w,            fc1T,      500, 500, 500,  512, 0, 0);
  addjob(3, fc2_w,            B2T,       500, 500, 500,  512, 0, 0);
  addjob(4, fc2_w + 250000,   B2T,       500, 500, 500,  512, 512, 0);
  addjob(5, fc3_w,            B34T,      500, 500, 500,  512, 0, 0);
  addjob(6, fc4_w,            B34T,      500, 100, 100,  512, 512, 0);
  addjob(7, fc6_w,            fc6T,      500, 500, 500, 1024, 0, 0);
  addjob(8, fc6_w + 250000,   fc6T,      500, 500, 500, 1024, 0, 512);
  jobs.total = base;
  pack_weights<<<base, tblk, 0, stream>>>(jobs);
  pack_biases<<<6, 1024, 0, stream>>>(ac_fc2_b, ac_lnf2_b, fc1_b, fc2_b, fc3_b, fc4_b, fc6_b,
                                      b_ac2p, b_lnf2p, b_f1p, b2p, b34p, b_f6p);

  // ---- a = LN(actions @ ac_fc1_w + b) ----
  gemm128<<<dim3(4, 4), blk, 0, stream>>>(actions, ac_fc1_w, ac_fc1_b, tmp_a, 512, 500, 64);
  ln_wave4<0, float, u16><<<32, blk, 0, stream>>>(tmp_a, a_buf, ac_ln1_g, ac_ln1_b, 500, 512);
  build_concat<<<8192, blk, 0, stream>>>(state, a_buf, cat);

  // ---- t1 = cat @ ac_fc2_w + b (bf16, dbuf 128x128 K=1024); att_a ----
  gemm_sq<u16><<<dim3(4, 64), blk, 0, stream>>>(cat, nullptr, ac_fc2T, b_ac2p,
                                                t1, 8192, 512, 1024, 1024, 0);
  dot_sig4<<<512, blk, 0, stream>>>(cat, ac_fc3_w, ac_fc3_b, att_a);
  // ---- s2 = (t1 @ ac_lnf2_w + b) * att_a ----
  gemm_mfma<u16><<<dim3(8, 64), blk, 0, stream>>>(t1, nullptr, ac_lnf2T, b_lnf2p, att_a,
                                                  s2, 8192, 512, 512, 512, 0);
  // ---- s1 = relu(LN(s2 @ fc1_w + b, ln1)); pre-LN bf16 (t1 reused) ----
  gemm_mfma<u16><<<dim3(8, 64), blk, 0, stream>>>(s2, nullptr, fc1T, b_f1p, nullptr,
                                                  t1, 8192, 512, 512, 512, 0);
  ln_wave4<1, u16, u16><<<512, blk, 0, stream>>>(t1, s1, ln1_g, ln1_b, 512, 512);
  // ---- PQ = s1 @ [fc2_w[:500] | fc2_w[500:]] (bf16, dbuf 128x128) ----
  gemm_sq<u16><<<dim3(8, 64), blk, 0, stream>>>(s1, nullptr, B2T, b2p,
                                                PQ, 8192, 1024, 512, 512, 0);

  // ---- chunk loop: 4096 pairs = 61440 core rows per iteration ----
  for (int c = 0; c < 2; ++c) {
    int c0 = c * 4096;
    core_build3<<<3840, blk, 0, stream>>>(PQ, core, ln2_g, ln2_b, c0);
    gemm_sq<u16><<<dim3(5, 480), blk, 0, stream>>>(core, nullptr, B34T, b34p,
                                                   v, 61440, 640, 512, 512, 0);
    chunk_post3<<<4096, blk, 0, stream>>>(v, ln3_g, ln3_b, ln4_g, ln4_b, fc5_w, fc5_b,
                                          esum16, c0);
  }

  // ---- h = LN([s1 | esum] @ fc6_w + b, ln6) — split-A dbuf 128x128 K=1024 ---
  gemm_sq<u16><<<dim3(4, 64), blk, 0, stream>>>(s1, esum16, fc6T, b_f6p,
                                                t1, 8192, 512, 1024, 512, 512);
  ln_wave4<0, u16, float><<<512, blk, 0, stream>>>(t1, out, ln6_g, ln6_b, 512, 500);
}

// Round 18
// 418.499 us; speedup vs baseline: 1.0211x; 1.0211x over previous
//
#include <hip/hip_runtime.h>
#include <math.h>

// TheRecurrentNet: B=512, K=16, H=500, A=64, nc=15.
// Round 18: revert round-17's K=1024 gemm_sq propagation (1 block/CU
// regression, 427us) back to the round-15/16 champion assignment (418.8us):
//   gemm_sq (dbuf 128x128, counted vmcnt): chunk GEMMs + PQ (>=2 blocks/CU)
//   gemm_mfma (dbuf 128x64, counted vmcnt): ac_fc2, s2, fc1, fc6 (N=512-class)
// Every GEMM is on its best A/B-measured variant. Bit-identical numerics.

#define EPSF 1e-5f
typedef unsigned short u16;
typedef unsigned int u32;

typedef __bf16 bf16x8 __attribute__((ext_vector_type(8)));
typedef float f32x4 __attribute__((ext_vector_type(4)));
typedef u16 u16x8 __attribute__((ext_vector_type(8)));

__device__ __forceinline__ float bf2f(u16 u) {
  return __builtin_bit_cast(float, (u32)u << 16);
}
__device__ __forceinline__ u16 f2bf(float f) {
  u32 u = __builtin_bit_cast(u32, f);
  return (u16)((u + 0x7FFFu + ((u >> 16) & 1u)) >> 16);   // RNE
}

#define GLOAD16(g, l) __builtin_amdgcn_global_load_lds( \
    (__attribute__((address_space(1))) u32*)(g), \
    (__attribute__((address_space(3))) u32*)(l), 16, 0, 0)

// ======================= bf16 MFMA GEMM, 128x64 tile, BK=64 ==================
// C[M,Npad] = A[M,K] @ Bt[Npad,K]^T + bias, optional *rowscale.
// A2: K-range [khalf,K) reads from A2 (split-A concat fusion).
// Double-buffered LDS, counted vmcnt, LDS XOR-swizzle, XCD col-fast swizzle.
template <typename TOUT>
__global__ __launch_bounds__(256) void gemm_mfma(
    const u16* __restrict__ A, const u16* __restrict__ A2,
    const u16* __restrict__ Bt,
    const float* __restrict__ bias, const float* __restrict__ rowscale,
    TOUT* __restrict__ C, int M, int Npad, int K, int lda, int khalf)
{
  __shared__ __align__(16) u16 As[2][128 * 64];
  __shared__ __align__(16) u16 Bs[2][64 * 64];
  const int tid = threadIdx.x;
  const int lane = tid & 63, wid = tid >> 6;

  const int ncols = gridDim.x;
  const int nwg = ncols * gridDim.y;
  const int bid = blockIdx.y * ncols + blockIdx.x;
  const int swz = (bid & 7) * (nwg >> 3) + (bid >> 3);
  const size_t row0 = (size_t)(swz / ncols) * 128;
  const size_t col0 = (size_t)(swz % ncols) * 64;

  f32x4 acc[2][4] = {};

  const int s_sub = tid >> 3;
  const int s_chunk = (tid & 7) ^ (s_sub & 7);
  const size_t aoff = (row0 + s_sub) * (size_t)lda + s_chunk * 8;
  const u16* gA = A + aoff;
  const u16* gA2 = A2 ? (A2 + aoff - khalf) : nullptr;
  const u16* gB = Bt + (col0 + s_sub) * (size_t)K + s_chunk * 8;

  const int fr = lane & 15, fq = lane >> 4;
  const int cx0 = fq ^ (fr & 7);
  const int cx1 = (4 + fq) ^ (fr & 7);

  const int nkt = K >> 6;
  int cur = 0;

  {
#pragma unroll
    for (int h = 0; h < 4; ++h)
      GLOAD16(gA + (size_t)h * 32 * lda, &As[0][(h * 256 + tid) * 8]);
#pragma unroll
    for (int h = 0; h < 2; ++h)
      GLOAD16(gB + (size_t)h * 32 * K, &Bs[0][(h * 256 + tid) * 8]);
  }

  for (int kt = 0; kt < nkt; ++kt) {
    if (kt + 1 < nkt) {
      const int kk = (kt + 1) * 64;
      const u16* a = (A2 && kk >= khalf) ? (gA2 + kk) : (gA + kk);
      const u16* b = gB + kk;
#pragma unroll
      for (int h = 0; h < 4; ++h)
        GLOAD16(a + (size_t)h * 32 * lda, &As[cur ^ 1][(h * 256 + tid) * 8]);
#pragma unroll
      for (int h = 0; h < 2; ++h)
        GLOAD16(b + (size_t)h * 32 * K, &Bs[cur ^ 1][(h * 256 + tid) * 8]);
      asm volatile("s_waitcnt vmcnt(6)" ::: "memory");
    } else {
      asm volatile("s_waitcnt vmcnt(0)" ::: "memory");
    }
    __builtin_amdgcn_sched_barrier(0);
    __builtin_amdgcn_s_barrier();
    __builtin_amdgcn_sched_barrier(0);

    const u16* as = As[cur];
    const u16* bs = Bs[cur];
#pragma unroll
    for (int ks = 0; ks < 2; ++ks) {
      const int cx = ks ? cx1 : cx0;
      bf16x8 af[2], bf[4];
#pragma unroll
      for (int m = 0; m < 2; ++m) {
        int row = wid * 32 + m * 16 + fr;
        af[m] = *reinterpret_cast<const bf16x8*>(as + (row * 8 + cx) * 8);
      }
#pragma unroll
      for (int n = 0; n < 4; ++n) {
        int row = n * 16 + fr;
        bf[n] = *reinterpret_cast<const bf16x8*>(bs + (row * 8 + cx) * 8);
      }
#pragma unroll
      for (int m = 0; m < 2; ++m)
#pragma unroll
        for (int n = 0; n < 4; ++n)
          acc[m][n] = __builtin_amdgcn_mfma_f32_16x16x32_bf16(af[m], bf[n], acc[m][n], 0, 0, 0);
    }
    asm volatile("s_waitcnt lgkmcnt(0)" ::: "memory");
    __builtin_amdgcn_sched_barrier(0);
    __builtin_amdgcn_s_barrier();
    __builtin_amdgcn_sched_barrier(0);
    cur ^= 1;
  }

  const int cl = lane & 15, rg = lane >> 4;
#pragma unroll
  for (int m = 0; m < 2; ++m) {
#pragma unroll
    for (int n = 0; n < 4; ++n) {
      size_t col = col0 + n * 16 + cl;
      float bv = bias[col];
#pragma unroll
      for (int r = 0; r < 4; ++r) {
        size_t row = row0 + wid * 32 + m * 16 + rg * 4 + r;
        float v = acc[m][n][r] + bv;
        if (rowscale) v *= rowscale[row];
        if constexpr (sizeof(TOUT) == 2) C[row * Npad + col] = f2bf(v);
        else                             C[row * Npad + col] = v;
      }
    }
  }
}

// ==== bf16 MFMA GEMM, 128x128 tile, BK=64, DOUBLE-buffer + counted vmcnt ====
// 4 waves each own a 64x64 quadrant (4x4 frags). Next K-tile's 8 loads stay
// in flight across the barrier (vmcnt(8)). A2: K-range [khalf,K) reads from
// A2 (khalf=0 disables). 64 KB LDS -> 2 blocks/CU. Needs grid >= 2 blocks/CU.
template <typename TOUT>
__global__ __launch_bounds__(256) void gemm_sq(
    const u16* __restrict__ A, const u16* __restrict__ A2,
    const u16* __restrict__ Bt,
    const float* __restrict__ bias,
    TOUT* __restrict__ C, int M, int Npad, int K, int lda, int khalf)
{
  __shared__ __align__(16) u16 As[2][128 * 64];
  __shared__ __align__(16) u16 Bs[2][128 * 64];
  const int tid = threadIdx.x;
  const int lane = tid & 63, wid = tid >> 6;
  const int ar0 = (wid >> 1) * 64;   // wave row base
  const int bc0 = (wid & 1) * 64;    // wave col base

  const int ncols = gridDim.x;
  const int nwg = ncols * gridDim.y;
  const int bid = blockIdx.y * ncols + blockIdx.x;
  const int swz = (bid & 7) * (nwg >> 3) + (bid >> 3);
  const size_t row0 = (size_t)(swz / ncols) * 128;
  const size_t col0 = (size_t)(swz % ncols) * 128;

  f32x4 acc[4][4] = {};

  const int s_sub = tid >> 3;
  const int s_chunk = (tid & 7) ^ (s_sub & 7);
  const size_t aoff = (row0 + s_sub) * (size_t)lda + s_chunk * 8;
  const u16* gA = A + aoff;
  const u16* gA2 = A2 ? (A2 + aoff - khalf) : nullptr;
  const u16* gB = Bt + (col0 + s_sub) * (size_t)K + s_chunk * 8;

  const int fr = lane & 15, fq = lane >> 4;
  const int cx0 = fq ^ (fr & 7);
  const int cx1 = (4 + fq) ^ (fr & 7);

  const int nkt = K >> 6;
  int cur = 0;

  // prologue: stage K-tile 0 into buffer 0 (8 loads)
  {
#pragma unroll
    for (int h = 0; h < 4; ++h) {
      GLOAD16(gA + (size_t)h * 32 * lda, &As[0][(h * 256 + tid) * 8]);
      GLOAD16(gB + (size_t)h * 32 * K,  &Bs[0][(h * 256 + tid) * 8]);
    }
  }

  for (int kt = 0; kt < nkt; ++kt) {
    if (kt + 1 < nkt) {
      const int kk = (kt + 1) * 64;
      const u16* a = (A2 && kk >= khalf) ? (gA2 + kk) : (gA + kk);
      const u16* b = gB + kk;
#pragma unroll
      for (int h = 0; h < 4; ++h) {
        GLOAD16(a + (size_t)h * 32 * lda, &As[cur ^ 1][(h * 256 + tid) * 8]);
        GLOAD16(b + (size_t)h * 32 * K,  &Bs[cur ^ 1][(h * 256 + tid) * 8]);
      }
      asm volatile("s_waitcnt vmcnt(8)" ::: "memory");   // wait tile kt only
    } else {
      asm volatile("s_waitcnt vmcnt(0)" ::: "memory");
    }
    __builtin_amdgcn_sched_barrier(0);
    __builtin_amdgcn_s_barrier();                        // tile kt ready
    __builtin_amdgcn_sched_barrier(0);

    const u16* as = As[cur];
    const u16* bs = Bs[cur];
#pragma unroll
    for (int ks = 0; ks < 2; ++ks) {
      const int cx = ks ? cx1 : cx0;
      bf16x8 af[4], bf[4];
#pragma unroll
      for (int m = 0; m < 4; ++m)
        af[m] = *reinterpret_cast<const bf16x8*>(as + ((ar0 + m * 16 + fr) * 8 + cx) * 8);
#pragma unroll
      for (int n = 0; n < 4; ++n)
        bf[n] = *reinterpret_cast<const bf16x8*>(bs + ((bc0 + n * 16 + fr) * 8 + cx) * 8);
#pragma unroll
      for (int m = 0; m < 4; ++m)
#pragma unroll
        for (int n = 0; n < 4; ++n)
          acc[m][n] = __builtin_amdgcn_mfma_f32_16x16x32_bf16(af[m], bf[n], acc[m][n], 0, 0, 0);
    }
    asm volatile("s_waitcnt lgkmcnt(0)" ::: "memory");
    __builtin_amdgcn_sched_barrier(0);
    __builtin_amdgcn_s_barrier();                        // safe to overwrite buf
    __builtin_amdgcn_sched_barrier(0);
    cur ^= 1;
  }

  const int cl = lane & 15, rg = lane >> 4;
#pragma unroll
  for (int m = 0; m < 4; ++m) {
#pragma unroll
    for (int n = 0; n < 4; ++n) {
      size_t col = col0 + bc0 + n * 16 + cl;
      float bv = bias[col];
#pragma unroll
      for (int r = 0; r < 4; ++r) {
        size_t row = row0 + ar0 + m * 16 + rg * 4 + r;
        float v = acc[m][n][r] + bv;
        if constexpr (sizeof(TOUT) == 2) C[row * Npad + col] = f2bf(v);
        else                             C[row * Npad + col] = v;
      }
    }
  }
}

// ---------------- small f32 GEMM (actions @ ac_fc1_w) ------------------------
__global__ __launch_bounds__(256) void gemm128(
    const float* __restrict__ A, const float* __restrict__ B,
    const float* __restrict__ bias, float* __restrict__ C, int M, int N, int K)
{
  __shared__ float As[16][132];
  __shared__ float Bs[16][128];
  const int tid = threadIdx.x;
  const int tx = tid & 15, ty = tid >> 4;
  const int row0 = blockIdx.y * 128, col0 = blockIdx.x * 128;
  float acc[8][8];
#pragma unroll
  for (int i = 0; i < 8; ++i)
#pragma unroll
    for (int j = 0; j < 8; ++j) acc[i][j] = 0.f;

  const int nkt = (K + 15) >> 4;
  for (int kt = 0; kt < nkt; ++kt) {
    const int k0 = kt << 4;
#pragma unroll
    for (int h = 0; h < 2; ++h) {
      int i = tid + h * 256;
      int m = i >> 2, kk = (i & 3) << 2;
      int gm = row0 + m, gk = k0 + kk;
      float4 v = make_float4(0.f, 0.f, 0.f, 0.f);
      if (gm < M && gk < K) v = *reinterpret_cast<const float4*>(A + (size_t)gm * K + gk);
      As[kk + 0][m] = v.x; As[kk + 1][m] = v.y; As[kk + 2][m] = v.z; As[kk + 3][m] = v.w;
    }
#pragma unroll
    for (int h = 0; h < 2; ++h) {
      int i = tid + h * 256;
      int kk = i >> 5, n = (i & 31) << 2;
      int gk = k0 + kk, gn = col0 + n;
      float4 v = make_float4(0.f, 0.f, 0.f, 0.f);
      if (gk < K && gn < N) v = *reinterpret_cast<const float4*>(B + (size_t)gk * N + gn);
      *reinterpret_cast<float4*>(&Bs[kk][n]) = v;
    }
    __syncthreads();
#pragma unroll
    for (int kk = 0; kk < 16; ++kk) {
      float4 a0 = *reinterpret_cast<const float4*>(&As[kk][ty * 4]);
      float4 a1 = *reinterpret_cast<const float4*>(&As[kk][ty * 4 + 64]);
      float4 b0 = *reinterpret_cast<const float4*>(&Bs[kk][tx * 4]);
      float4 b1 = *reinterpret_cast<const float4*>(&Bs[kk][tx * 4 + 64]);
      float av[8] = {a0.x, a0.y, a0.z, a0.w, a1.x, a1.y, a1.z, a1.w};
      float bv[8] = {b0.x, b0.y, b0.z, b0.w, b1.x, b1.y, b1.z, b1.w};
#pragma unroll
      for (int i = 0; i < 8; ++i)
#pragma unroll
        for (int j = 0; j < 8; ++j) acc[i][j] += av[i] * bv[j];
    }
    __syncthreads();
  }
#pragma unroll
  for (int i = 0; i < 8; ++i) {
    int gm = row0 + ty * 4 + ((i >> 2) << 6) + (i & 3);
    if (gm >= M) continue;
#pragma unroll
    for (int j = 0; j < 8; ++j) {
      int gn = col0 + tx * 4 + ((j >> 2) << 6) + (j & 3);
      if (gn < N) C[(size_t)gm * N + gn] = acc[i][j] + bias[gn];
    }
  }
}

// ------------- wave-per-4-rows LayerNorm (cols=500) --------------------------
template <int ACT, typename TIN, typename TOUT>
__global__ __launch_bounds__(256) void ln_wave4(
    const TIN* __restrict__ X, TOUT* __restrict__ Y,
    const float* __restrict__ g, const float* __restrict__ b,
    int ldx, int ldy)
{
  int w = threadIdx.x >> 6, lane = threadIdx.x & 63;
  int id0 = (blockIdx.x * 4 + w) * 4;
  int k0 = lane * 8;
  float xv[4][8], s[4], s2[4];
#pragma unroll
  for (int r = 0; r < 4; ++r) {
    s[r] = 0.f; s2[r] = 0.f;
    if constexpr (sizeof(TIN) == 2) {
      u16x8 u = *reinterpret_cast<const u16x8*>((const u16*)X + (size_t)(id0 + r) * ldx + k0);
#pragma unroll
      for (int e = 0; e < 8; ++e) xv[r][e] = bf2f(u[e]);
    } else {
      const float* x = (const float*)X + (size_t)(id0 + r) * ldx;
      if (k0 + 8 <= 500) {
        float4 a = *reinterpret_cast<const float4*>(x + k0);
        float4 c = *reinterpret_cast<const float4*>(x + k0 + 4);
        xv[r][0] = a.x; xv[r][1] = a.y; xv[r][2] = a.z; xv[r][3] = a.w;
        xv[r][4] = c.x; xv[r][5] = c.y; xv[r][6] = c.z; xv[r][7] = c.w;
      } else {
#pragma unroll
        for (int e = 0; e < 8; ++e) xv[r][e] = (k0 + e < 500) ? x[k0 + e] : 0.f;
      }
    }
#pragma unroll
    for (int e = 0; e < 8; ++e) { s[r] += xv[r][e]; s2[r] += xv[r][e] * xv[r][e]; }
  }
#pragma unroll
  for (int m = 32; m; m >>= 1)
#pragma unroll
    for (int r = 0; r < 4; ++r) {
      s[r] += __shfl_xor(s[r], m);
      s2[r] += __shfl_xor(s2[r], m);
    }
  float gv[8], bv[8];
#pragma unroll
  for (int e = 0; e < 8; ++e) {
    int k = k0 + e;
    gv[e] = (k < 500) ? g[k] : 0.f;
    bv[e] = (k < 500) ? b[k] : 0.f;
  }
#pragma unroll
  for (int r = 0; r < 4; ++r) {
    float mu = s[r] / 500.f;
    float rstd = rsqrtf(s2[r] / 500.f - mu * mu + EPSF);
    float ov[8];
#pragma unroll
    for (int e = 0; e < 8; ++e) {
      float v = (k0 + e < 500) ? ((xv[r][e] - mu) * rstd * gv[e] + bv[e]) : 0.f;
      if (ACT == 1) v = fmaxf(v, 0.f);
      ov[e] = v;
    }
    if constexpr (sizeof(TOUT) == 2) {
      u16x8 o;
#pragma unroll
      for (int e = 0; e < 8; ++e) o[e] = f2bf(ov[e]);
      *reinterpret_cast<u16x8*>((u16*)Y + (size_t)(id0 + r) * ldy + k0) = o;
    } else {
      float* y = (float*)Y + (size_t)(id0 + r) * ldy;
      if (k0 + 4 <= 500)
        *reinterpret_cast<float4*>(y + k0) = make_float4(ov[0], ov[1], ov[2], ov[3]);
      if (k0 + 8 <= 500)
        *reinterpret_cast<float4*>(y + k0 + 4) = make_float4(ov[4], ov[5], ov[6], ov[7]);
    }
  }
}

// ---------------- cat[r] = [bf16(state[r]) | a[r>>4] | 0pad] -----------------
__global__ __launch_bounds__(256) void build_concat(
    const float* __restrict__ state, const u16* __restrict__ a, u16* __restrict__ cat)
{
  int r = blockIdx.x, t = threadIdx.x;
  int b = r >> 4;
  u16* c = cat + (size_t)r * 1024;
  if (t < 125) {
    float4 v = *reinterpret_cast<const float4*>(state + (size_t)r * 500 + t * 4);
    ushort4 o; o.x = f2bf(v.x); o.y = f2bf(v.y); o.z = f2bf(v.z); o.w = f2bf(v.w);
    *reinterpret_cast<ushort4*>(c + t * 4) = o;
    *reinterpret_cast<ushort4*>(c + 500 + t * 4) =
        *reinterpret_cast<const ushort4*>(a + (size_t)b * 512 + t * 4);
  }
  if (t < 24) c[1000 + t] = 0;
}

// -------- att_a: 4 rows per wave ---------------------------------------------
__global__ __launch_bounds__(256) void dot_sig4(
    const u16* __restrict__ cat, const float* __restrict__ w3,
    const float* __restrict__ b3, float* __restrict__ atta)
{
  int w = threadIdx.x >> 6, lane = threadIdx.x & 63;
  int r0 = (blockIdx.x * 4 + w) * 4;
  int k0 = lane * 16;
  float wv[16];
#pragma unroll
  for (int e = 0; e < 16; ++e) wv[e] = (k0 + e < 1000) ? w3[k0 + e] : 0.f;
  float s[4];
#pragma unroll
  for (int r = 0; r < 4; ++r) {
    const u16* x = cat + (size_t)(r0 + r) * 1024 + k0;
    u16x8 u0 = *reinterpret_cast<const u16x8*>(x);
    u16x8 u1 = *reinterpret_cast<const u16x8*>(x + 8);
    float acc = 0.f;
#pragma unroll
    for (int e = 0; e < 8; ++e) acc += bf2f(u0[e]) * wv[e];
#pragma unroll
    for (int e = 0; e < 8; ++e) acc += bf2f(u1[e]) * wv[8 + e];
    s[r] = acc;
  }
#pragma unroll
  for (int m = 32; m; m >>= 1)
#pragma unroll
    for (int r = 0; r < 4; ++r) s[r] += __shfl_xor(s[r], m);
  if (lane == 0) {
#pragma unroll
    for (int r = 0; r < 4; ++r)
      atta[r0 + r] = 1.f / (1.f + expf(-(s[r] + b3[0])));
  }
}

// -------- core rows = relu(LN(P[r1]+Q[r2], ln2)) — 4 rows/wave, bf16 ---------
__global__ __launch_bounds__(256) void core_build3(
    const u16* __restrict__ PQ, u16* __restrict__ core,
    const float* __restrict__ g2, const float* __restrict__ b2, int c0)
{
  int w = threadIdx.x >> 6, lane = threadIdx.x & 63;
  int id0 = (blockIdx.x * 4 + w) * 4;
  int k0 = lane * 8;
  u16x8 up[4], uq[4];
#pragma unroll
  for (int r = 0; r < 4; ++r) {
    int id = id0 + r;
    int pp = id / 15, j = id - pp * 15;
    int gp = c0 + pp, i = gp & 15;
    int col = j + (j >= i);
    int r2 = (gp & ~15) | col;
    up[r] = *reinterpret_cast<const u16x8*>(PQ + (size_t)gp * 1024 + k0);
    uq[r] = *reinterpret_cast<const u16x8*>(PQ + (size_t)r2 * 1024 + 512 + k0);
  }
  float xv[4][8], s[4], s2[4];
#pragma unroll
  for (int r = 0; r < 4; ++r) {
    s[r] = 0.f; s2[r] = 0.f;
#pragma unroll
    for (int e = 0; e < 8; ++e) {
      float v = bf2f(up[r][e]) + bf2f(uq[r][e]);   // pads are exact zeros
      xv[r][e] = v; s[r] += v; s2[r] += v * v;
    }
  }
#pragma unroll
  for (int m = 32; m; m >>= 1)
#pragma unroll
    for (int r = 0; r < 4; ++r) {
      s[r] += __shfl_xor(s[r], m);
      s2[r] += __shfl_xor(s2[r], m);
    }
  float gv[8], bv[8];
#pragma unroll
  for (int e = 0; e < 8; ++e) {
    int k = k0 + e;
    gv[e] = (k < 500) ? g2[k] : 0.f;
    bv[e] = (k < 500) ? b2[k] : 0.f;
  }
#pragma unroll
  for (int r = 0; r < 4; ++r) {
    float mu = s[r] / 500.f;
    float rstd = rsqrtf(s2[r] / 500.f - mu * mu + EPSF);
    u16x8 o;
#pragma unroll
    for (int e = 0; e < 8; ++e)
      o[e] = (k0 + e < 500) ? f2bf(fmaxf((xv[r][e] - mu) * rstd * gv[e] + bv[e], 0.f)) : (u16)0;
    *reinterpret_cast<u16x8*>(core + (size_t)(id0 + r) * 512 + k0) = o;
  }
}

// -------- fused chunk tail -> esum in PADDED BF16 (feeds fc6 split-A) --------
__global__ __launch_bounds__(256) void chunk_post3(
    const u16* __restrict__ V,
    const float* __restrict__ g3, const float* __restrict__ b3,
    const float* __restrict__ g4, const float* __restrict__ b4,
    const float* __restrict__ w5, const float* __restrict__ b5,
    u16* __restrict__ esum16, int c0)
{
  __shared__ u16 rows[15][512];
  __shared__ float st[15][4];   // mu, rstd, att
  int pp = blockIdx.x, t = threadIdx.x;
  int lane = t & 63, w = t >> 6;
  int k0 = lane * 8;
  int kk = lane * 2;

  u16x8 u[4]; ushort2 ua[4];
#pragma unroll
  for (int r = 0; r < 4; ++r) {
    int j = w * 4 + r;
    if (j < 15) {
      const u16* vr = V + (size_t)(pp * 15 + j) * 640;
      u[r] = *reinterpret_cast<const u16x8*>(vr + k0);
      ua[r] = *reinterpret_cast<const ushort2*>(vr + 512 + kk);
    }
  }
  float s[4], s2[4], sa[4], sa2[4], y0[4], y1[4];
#pragma unroll
  for (int r = 0; r < 4; ++r) {
    s[r] = s2[r] = sa[r] = sa2[r] = 0.f; y0[r] = y1[r] = 0.f;
    int j = w * 4 + r;
    if (j < 15) {
#pragma unroll
      for (int e = 0; e < 8; ++e) { float v = bf2f(u[r][e]); s[r] += v; s2[r] += v * v; }
      y0[r] = bf2f(ua[r].x); y1[r] = bf2f(ua[r].y);
      sa[r] = y0[r] + y1[r]; sa2[r] = y0[r] * y0[r] + y1[r] * y1[r];
      *reinterpret_cast<u16x8*>(&rows[j][k0]) = u[r];
    }
  }
#pragma unroll
  for (int m = 32; m; m >>= 1)
#pragma unroll
    for (int r = 0; r < 4; ++r) {
      s[r]   += __shfl_xor(s[r], m);
      s2[r]  += __shfl_xor(s2[r], m);
      sa[r]  += __shfl_xor(sa[r], m);
      sa2[r] += __shfl_xor(sa2[r], m);
    }
  float dv[4];
#pragma unroll
  for (int r = 0; r < 4; ++r) {
    float mu4 = sa[r] / 100.f;
    float rstd4 = rsqrtf(sa2[r] / 100.f - mu4 * mu4 + EPSF);
    float d = 0.f;
    if (kk < 100)     d += tanhf((y0[r] - mu4) * rstd4 * g4[kk] + b4[kk]) * w5[kk];
    if (kk + 1 < 100) d += tanhf((y1[r] - mu4) * rstd4 * g4[kk + 1] + b4[kk + 1]) * w5[kk + 1];
    dv[r] = d;
  }
#pragma unroll
  for (int m = 32; m; m >>= 1)
#pragma unroll
    for (int r = 0; r < 4; ++r) dv[r] += __shfl_xor(dv[r], m);
  if (lane == 0) {
#pragma unroll
    for (int r = 0; r < 4; ++r) {
      int j = w * 4 + r;
      if (j < 15) {
        float mu = s[r] / 500.f;
        st[j][0] = mu;
        st[j][1] = rsqrtf(s2[r] / 500.f - mu * mu + EPSF);
        st[j][2] = 1.f / (1.f + expf(-(dv[r] + b5[0])));
      }
    }
  }
  __syncthreads();

  u16* o = esum16 + (size_t)(c0 + pp) * 512;
  for (int n = t; n < 500; n += 256) {
    float gg = g3[n], bb = b3[n], acc = 0.f;
#pragma unroll
    for (int j = 0; j < 15; ++j) {
      float v = bf2f(rows[j][n]);
      acc += fmaxf((v - st[j][0]) * st[j][1] * gg + bb, 0.f) * st[j][2];
    }
    o[n] = f2bf(acc);
  }
  if (t < 12) o[500 + t] = 0;
}

// -------- merged transpose+pack: all 9 weight jobs in one dispatch -----------
struct TJob {
  const float* src; u16* dst;
  int K, N, srcLd, ldDst, nOff, kOff, tileBase, tilesX;
};
struct TJobs { TJob j[9]; int total; };

__global__ void pack_weights(TJobs jobs)
{
  __shared__ float tl[32][33];
  int bid = blockIdx.x;
  int ji = 0;
#pragma unroll
  for (int q = 1; q < 9; ++q) if (bid >= jobs.j[q].tileBase) ji = q;
  const TJob& J = jobs.j[ji];
  int t = bid - J.tileBase;
  int bx = t % J.tilesX, by = t / J.tilesX;
  int tx = threadIdx.x, ty = threadIdx.y;   // 32 x 8
  int k0 = by * 32, n0 = bx * 32;
#pragma unroll
  for (int r = 0; r < 4; ++r) {
    int row = k0 + ty + r * 8;
    if (row < J.K && n0 + tx < J.N) tl[ty + r * 8][tx] = J.src[(size_t)row * J.srcLd + n0 + tx];
  }
  __syncthreads();
#pragma unroll
  for (int r = 0; r < 4; ++r) {
    int n = n0 + ty + r * 8, k = k0 + tx;
    if (n < J.N && k < J.K)
      J.dst[(size_t)(n + J.nOff) * J.ldDst + J.kOff + k] = f2bf(tl[tx][ty + r * 8]);
  }
}

// -------- pack padded biases --------------------------------------------------
__global__ void pack_biases(
    const float* ac2, const float* lnf2, const float* f1, const float* f2,
    const float* f3, const float* f4, const float* f6,
    float* b_ac2p, float* b_lnf2p, float* b_f1p, float* b2p, float* b34p, float* b_f6p)
{
  int t = threadIdx.x;  // 1024
  switch (blockIdx.x) {
    case 0: if (t < 512) b_ac2p[t]  = (t < 500) ? ac2[t]  : 0.f; break;
    case 1: if (t < 512) b_lnf2p[t] = (t < 500) ? lnf2[t] : 0.f; break;
    case 2: if (t < 512) b_f1p[t]   = (t < 500) ? f1[t]   : 0.f; break;
    case 3: b2p[t] = (t < 500) ? f2[t] : 0.f; break;
    case 4: if (t < 640) b34p[t] = (t < 500) ? f3[t] : ((t >= 512 && t < 612) ? f4[t - 512] : 0.f); break;
    case 5: if (t < 512) b_f6p[t]   = (t < 500) ? f6[t]   : 0.f; break;
  }
}

extern "C" void kernel_launch(void* const* d_in, const int* in_sizes, int n_in,
                              void* d_out, int out_size, void* d_ws, size_t ws_size,
                              hipStream_t stream)
{
  const float* state    = (const float*)d_in[0];
  const float* actions  = (const float*)d_in[1];
  const float* ac_fc1_w = (const float*)d_in[2];
  const float* ac_fc1_b = (const float*)d_in[3];
  const float* ac_ln1_g = (const float*)d_in[4];
  const float* ac_ln1_b = (const float*)d_in[5];
  const float* ac_fc2_w = (const float*)d_in[6];
  const float* ac_fc2_b = (const float*)d_in[7];
  const float* ac_lnf2_w= (const float*)d_in[8];
  const float* ac_lnf2_b= (const float*)d_in[9];
  const float* ac_fc3_w = (const float*)d_in[10];
  const float* ac_fc3_b = (const float*)d_in[11];
  const float* fc1_w = (const float*)d_in[12];
  const float* fc1_b = (const float*)d_in[13];
  const float* ln1_g = (const float*)d_in[14];
  const float* ln1_b = (const float*)d_in[15];
  const float* fc2_w = (const float*)d_in[16];
  const float* fc2_b = (const float*)d_in[17];
  const float* ln2_g = (const float*)d_in[18];
  const float* ln2_b = (const float*)d_in[19];
  const float* fc3_w = (const float*)d_in[20];
  const float* fc3_b = (const float*)d_in[21];
  const float* ln3_g = (const float*)d_in[22];
  const float* ln3_b = (const float*)d_in[23];
  const float* fc4_w = (const float*)d_in[24];
  const float* fc4_b = (const float*)d_in[25];
  const float* ln4_g = (const float*)d_in[26];
  const float* ln4_b = (const float*)d_in[27];
  const float* fc5_w = (const float*)d_in[28];
  const float* fc5_b = (const float*)d_in[29];
  const float* fc6_w = (const float*)d_in[30];
  const float* fc6_b = (const float*)d_in[31];
  const float* ln6_g = (const float*)d_in[32];
  const float* ln6_b = (const float*)d_in[33];
  float* out = (float*)d_out;

  // ---- ws carve (bytes, 256-aligned); total ~215 MB ----
  char* p = (char*)d_ws;
  auto carve = [&](size_t bytes) { char* r = p; p += (bytes + 255) & ~(size_t)255; return r; };
  u16*   cat    = (u16*)  carve(8192ull * 1024 * 2);
  u16*   t1     = (u16*)  carve(8192ull * 512 * 2);    // ac_fc2 out, later fc1/fc6 pre-LN
  u16*   s2     = (u16*)  carve(8192ull * 512 * 2);
  u16*   s1     = (u16*)  carve(8192ull * 512 * 2);
  u16*   core   = (u16*)  carve(61440ull * 512 * 2);
  u16*   v      = (u16*)  carve(61440ull * 640 * 2);
  u16*   PQ     = (u16*)  carve(8192ull * 1024 * 2);
  u16*   esum16 = (u16*)  carve(8192ull * 512 * 2);
  u16*   a_buf  = (u16*)  carve(512ull * 512 * 2);
  float* tmp_a  = (float*)carve(512ull * 500 * 4);
  float* att_a  = (float*)carve(8192ull * 4);
  char*  wT0    =         carve(0);
  u16*   ac_fc2T  = (u16*)carve(512ull * 1024 * 2);
  u16*   ac_lnf2T = (u16*)carve(512ull * 512 * 2);
  u16*   fc1T     = (u16*)carve(512ull * 512 * 2);
  u16*   B2T      = (u16*)carve(1024ull * 512 * 2);
  u16*   B34T     = (u16*)carve(640ull * 512 * 2);
  u16*   fc6T     = (u16*)carve(512ull * 1024 * 2);
  size_t wTbytes  = (size_t)((char*)carve(0) - wT0);
  float* b_ac2p  = (float*)carve(512 * 4);
  float* b_lnf2p = (float*)carve(512 * 4);
  float* b_f1p   = (float*)carve(512 * 4);
  float* b2p     = (float*)carve(1024 * 4);
  float* b34p    = (float*)carve(640 * 4);
  float* b_f6p   = (float*)carve(512 * 4);

  dim3 blk(256);
  dim3 tblk(32, 8);

  // ---- weight packing: one memset + one merged transpose dispatch ----
  hipMemsetAsync(wT0, 0, wTbytes, stream);
  TJobs jobs;
  int base = 0;
  auto addjob = [&](int idx, const float* src, u16* dst, int K, int N, int srcLd,
                    int ldDst, int nOff, int kOff) {
    int tx = (N + 31) / 32, ty = (K + 31) / 32;
    jobs.j[idx] = {src, dst, K, N, srcLd, ldDst, nOff, kOff, base, tx};
    base += tx * ty;
  };
  addjob(0, ac_fc2_w,         ac_fc2T,  1000, 500, 500, 1024, 0, 0);
  addjob(1, ac_lnf2_w,        ac_lnf2T,  500, 500, 500,  512, 0, 0);
  addjob(2, fc1_w,            fc1T,      500, 500, 500,  512, 0, 0);
  addjob(3, fc2_w,            B2T,       500, 500, 500,  512, 0, 0);
  addjob(4, fc2_w + 250000,   B2T,       500, 500, 500,  512, 512, 0);
  addjob(5, fc3_w,            B34T,      500, 500, 500,  512, 0, 0);
  addjob(6, fc4_w,            B34T,      500, 100, 100,  512, 512, 0);
  addjob(7, fc6_w,            fc6T,      500, 500, 500, 1024, 0, 0);
  addjob(8, fc6_w + 250000,   fc6T,      500, 500, 500, 1024, 0, 512);
  jobs.total = base;
  pack_weights<<<base, tblk, 0, stream>>>(jobs);
  pack_biases<<<6, 1024, 0, stream>>>(ac_fc2_b, ac_lnf2_b, fc1_b, fc2_b, fc3_b, fc4_b, fc6_b,
                                      b_ac2p, b_lnf2p, b_f1p, b2p, b34p, b_f6p);

  // ---- a = LN(actions @ ac_fc1_w + b) ----
  gemm128<<<dim3(4, 4), blk, 0, stream>>>(actions, ac_fc1_w, ac_fc1_b, tmp_a, 512, 500, 64);
  ln_wave4<0, float, u16><<<32, blk, 0, stream>>>(tmp_a, a_buf, ac_ln1_g, ac_ln1_b, 500, 512);
  build_concat<<<8192, blk, 0, stream>>>(state, a_buf, cat);

  // ---- t1 = cat @ ac_fc2_w + b (bf16); att_a ----
  gemm_mfma<u16><<<dim3(8, 64), blk, 0, stream>>>(cat, nullptr, ac_fc2T, b_ac2p, nullptr,
                                                  t1, 8192, 512, 1024, 1024, 0);
  dot_sig4<<<512, blk, 0, stream>>>(cat, ac_fc3_w, ac_fc3_b, att_a);
  // ---- s2 = (t1 @ ac_lnf2_w + b) * att_a ----
  gemm_mfma<u16><<<dim3(8, 64), blk, 0, stream>>>(t1, nullptr, ac_lnf2T, b_lnf2p, att_a,
                                                  s2, 8192, 512, 512, 512, 0);
  // ---- s1 = relu(LN(s2 @ fc1_w + b, ln1)); pre-LN bf16 (t1 reused) ----
  gemm_mfma<u16><<<dim3(8, 64), blk, 0, stream>>>(s2, nullptr, fc1T, b_f1p, nullptr,
                                                  t1, 8192, 512, 512, 512, 0);
  ln_wave4<1, u16, u16><<<512, blk, 0, stream>>>(t1, s1, ln1_g, ln1_b, 512, 512);
  // ---- PQ = s1 @ [fc2_w[:500] | fc2_w[500:]] (bf16, dbuf 128x128) ----
  gemm_sq<u16><<<dim3(8, 64), blk, 0, stream>>>(s1, nullptr, B2T, b2p,
                                                PQ, 8192, 1024, 512, 512, 0);

  // ---- chunk loop: 4096 pairs = 61440 core rows per iteration ----
  for (int c = 0; c < 2; ++c) {
    int c0 = c * 4096;
    core_build3<<<3840, blk, 0, stream>>>(PQ, core, ln2_g, ln2_b, c0);
    gemm_sq<u16><<<dim3(5, 480), blk, 0, stream>>>(core, nullptr, B34T, b34p,
                                                   v, 61440, 640, 512, 512, 0);
    chunk_post3<<<4096, blk, 0, stream>>>(v, ln3_g, ln3_b, ln4_g, ln4_b, fc5_w, fc5_b,
                                          esum16, c0);
  }

  // ---- h = LN([s1 | esum] @ fc6_w + b, ln6) — split-A GEMM ----
  gemm_mfma<u16><<<dim3(8, 64), blk, 0, stream>>>(s1, esum16, fc6T, b_f6p, nullptr,
                                                  t1, 8192, 512, 1024, 512, 512);
  ln_wave4<0, u16, float><<<512, blk, 0, stream>>>(t1, out, ln6_g, ln6_b, 512, 500);
}